// Round 1
// baseline (6006.293 us; speedup 1.0000x reference)
//
#include <hip/hip_runtime.h>

constexpr int NB  = 32;     // batch
constexpr int NMX = 256;    // NMAX
constexpr int ED  = 512;    // E
constexpr int HD  = 512;    // H
constexpr int UD  = 256;    // U
constexpr int MS  = 32;     // M steps
constexpr int PD  = 4;      // P
constexpr int SD  = 257;    // S = NMAX+1
constexpr int IL0 = 547;    // E + (M-1) + P

constexpr long long OFF_PTR  = 0;
constexpr long long OFF_COVL = (long long)NB*SD*MS;              // 263168
constexpr long long OFF_ENC  = OFF_COVL + 1;                     // 263169
constexpr long long OFF_ADJ  = OFF_ENC + (long long)NB*SD*ED;    // 4473857
constexpr long long OFF_ATT  = OFF_ADJ + (long long)NB*(MS-1)*MS;// 4505601

__device__ __forceinline__ float sigf(float x){ return 1.0f/(1.0f + expf(-x)); }

// ---- encoder_out -> d_out[OFF_ENC]  (one block per (b,s) row) ----
__global__ void k_enc(const float* __restrict__ hp, const float* __restrict__ embsp,
                      const int* __restrict__ nn, float* __restrict__ out){
  int r = blockIdx.x; int b = r / SD, s = r % SD;
  float* dst = out + OFF_ENC + (long long)r*ED;
  int t = threadIdx.x;              // 128 threads, 4 floats each = 512
  if (s == 0){
    const float* src = embsp + ED;  // emb_special[1]
    int e = t*4; float4 v = *(const float4*)(src + e);
    dst[e] = v.x; dst[e+1] = v.y; dst[e+2] = v.z; dst[e+3] = v.w;
  } else if (s-1 < nn[b]){
    const float* src = hp + ((long long)b*NMX + (s-1))*ED;
    int e = t*4; float4 v = *(const float4*)(src + e);
    dst[e] = v.x; dst[e+1] = v.y; dst[e+2] = v.z; dst[e+3] = v.w;
  } else {
    int e = t*4;
    dst[e] = 0.f; dst[e+1] = 0.f; dst[e+2] = 0.f; dst[e+3] = 0.f;
  }
}

// ---- misc init: xT (step-0 input, transposed), hgT, cov=0, covl=0, W1T ----
__global__ void k_misc(const float* __restrict__ hg, const float* __restrict__ embsp,
                       const float* __restrict__ embpos, const float* __restrict__ W1,
                       float* __restrict__ xT, float* __restrict__ hgT,
                       float* __restrict__ cov, float* __restrict__ covl,
                       float* __restrict__ W1T){
  int idx = blockIdx.x*blockDim.x + threadIdx.x;
  const int N0 = IL0*NB;            // 17504
  const int N1 = N0 + ED*NB;        // +16384
  const int N2 = N1 + NB*SD;        // +8224
  const int N3 = N2 + NB;           // +32
  const int N4 = N3 + UD*ED;        // +131072
  for (int i = idx; i < N4; i += gridDim.x*blockDim.x){
    if (i < N0){
      int k = i / NB;
      float v;
      if (k < ED) v = embsp[k];                       // emb_special[0]
      else if (k < ED + MS - 1) v = 0.f;              // theta0 = 0
      else v = embpos[k - (ED + MS - 1)];             // emb_pos[0][p]
      xT[i] = v;
    } else if (i < N1){
      int j = i - N0; int k = j / NB, b = j % NB;
      hgT[j] = hg[(long long)b*ED + k];
    } else if (i < N2){
      cov[i - N1] = 0.f;
    } else if (i < N3){
      covl[i - N2] = 0.f;
    } else {
      int j = i - N3; int k = j / UD, u = j % UD;
      W1T[j] = W1[(long long)u*ED + k];
    }
  }
}

// ---- enc_W1[b][s][u] = encoder_out[b,s,:] @ W1[u,:]   (wave handles 8 s-rows) ----
__global__ void k_encw1(const float* __restrict__ out, const float* __restrict__ W1T,
                        float* __restrict__ encW1){
  int wave = blockIdx.x*4 + (threadIdx.x >> 6);    // 0..1055
  int lane = threadIdx.x & 63;
  int b = wave / 33, g = wave % 33;
  int s0 = g*8;
  const float* base = out + OFF_ENC + (long long)b*SD*ED;
  const float* ar[8];
  #pragma unroll
  for (int j = 0; j < 8; ++j){
    int s = s0 + j; if (s > SD-1) s = SD-1;
    ar[j] = base + (long long)s*ED;
  }
  float4 acc[8];
  #pragma unroll
  for (int j = 0; j < 8; ++j) acc[j] = {0.f,0.f,0.f,0.f};
  for (int k = 0; k < ED; ++k){
    float4 w = *(const float4*)(W1T + (long long)k*UD + lane*4);
    #pragma unroll
    for (int j = 0; j < 8; ++j){
      float a = ar[j][k];
      acc[j].x += a*w.x; acc[j].y += a*w.y; acc[j].z += a*w.z; acc[j].w += a*w.w;
    }
  }
  #pragma unroll
  for (int j = 0; j < 8; ++j){
    int s = s0 + j;
    if (s < SD)
      *(float4*)(encW1 + ((long long)b*SD + s)*UD + lane*4) = acc[j];
  }
}

// ---- dec_hidden init: tanh(hg @ Wp.T + bp) -> h0T/h1T (transposed [H][B]) ----
__global__ void k_hid0(const float* __restrict__ hgT, const float* __restrict__ Wp,
                       const float* __restrict__ bp, float* __restrict__ h0T,
                       float* __restrict__ h1T){
  int t = threadIdx.x; int b = t & 31;
  int row = blockIdx.x*8 + (t >> 5);               // 0..1023
  const float* w = Wp + (long long)row*ED;
  float acc = bp[row];
  #pragma unroll 4
  for (int k = 0; k < ED; ++k) acc += hgT[k*NB + b] * w[k];
  float v = tanhf(acc);
  if (row < HD) h0T[row*NB + b] = v;
  else          h1T[(row - HD)*NB + b] = v;
}

// ---- one GRU layer step. xT: [IL][B], hT: [H][B] (prev), outT: [H][B] (new) ----
// block = 192 threads = 32 b x 3 gates x 2 h;  grid = 256 (h pairs)
template<int IL>
__global__ void k_gru(const float* __restrict__ xT, const float* __restrict__ hT,
                      const float* __restrict__ Wih, const float* __restrict__ Whh,
                      const float* __restrict__ bih, const float* __restrict__ bhh,
                      float* __restrict__ outT){
  __shared__ float li[2][3][NB];
  __shared__ float lh[2][3][NB];
  int t = threadIdx.x;
  int b = t & 31;
  int gh = t >> 5;                 // 0..5
  int g = gh % 3, hl = gh / 3;
  int h = blockIdx.x*2 + hl;
  int row = g*HD + h;
  const float* wi = Wih + (long long)row*IL;
  float ai = 0.f;
  #pragma unroll 4
  for (int k = 0; k < IL; ++k) ai += xT[k*NB + b] * wi[k];
  const float* wh = Whh + (long long)row*HD;
  float ah = 0.f;
  #pragma unroll 4
  for (int k = 0; k < HD; ++k) ah += hT[k*NB + b] * wh[k];
  li[hl][g][b] = ai + bih[row];
  lh[hl][g][b] = ah + bhh[row];
  __syncthreads();
  if (t < 64){
    int b2 = t & 31, hl2 = t >> 5;
    int h2 = blockIdx.x*2 + hl2;
    float r = sigf(li[hl2][0][b2] + lh[hl2][0][b2]);
    float z = sigf(li[hl2][1][b2] + lh[hl2][1][b2]);
    float nn = tanhf(li[hl2][2][b2] + r*lh[hl2][2][b2]);
    float hp = hT[h2*NB + b2];
    outT[h2*NB + b2] = (1.f - z)*nn + z*hp;
  }
}

// ---- q = out@W2.T ; theta = sigmoid(out@Wf.T+bf) (0 at m=0) -> xT + adj; pe for next ----
__global__ void k_qk(const float* __restrict__ outT, const float* __restrict__ W2,
                     const float* __restrict__ Wf, const float* __restrict__ bfv,
                     const float* __restrict__ embpos, int m,
                     float* __restrict__ q, float* __restrict__ xT,
                     float* __restrict__ out){
  int t = threadIdx.x; int b = t & 31; int loc = t >> 5;
  int wg = blockIdx.x;
  if (wg < 32){
    int u = wg*8 + loc;
    const float* w = W2 + (long long)u*HD;
    float acc = 0.f;
    #pragma unroll 4
    for (int k = 0; k < HD; ++k) acc += outT[k*NB + b] * w[k];
    q[b*UD + u] = acc;
  } else {
    int j = (wg - 32)*8 + loc;
    if (j < MS-1){
      const float* w = Wf + (long long)j*HD;
      float acc = bfv[j];
      #pragma unroll 4
      for (int k = 0; k < HD; ++k) acc += outT[k*NB + b] * w[k];
      float th = (m < 1) ? 0.f : sigf(acc);
      xT[(ED + j)*NB + b] = th;
      out[OFF_ADJ + (long long)b*(MS-1)*MS + (long long)j*MS + m] = th;
    }
    if (wg == 35 && loc == 0 && m + 1 < MS){
      #pragma unroll
      for (int p = 0; p < PD; ++p)
        xT[(ED + MS - 1 + p)*NB + b] = embpos[(m+1)*PD + p];
    }
  }
}

// ---- attention scores: wave per (b,s) ----
__global__ void k_scores(const float* __restrict__ encW1, const float* __restrict__ q,
                         const float* __restrict__ wc, const float* __restrict__ V,
                         const float* __restrict__ cov, float* __restrict__ sc){
  int wave = blockIdx.x*4 + (threadIdx.x >> 6);   // 0..8223
  int lane = threadIdx.x & 63;
  int b = wave / SD, s = wave % SD;
  float4 q4 = *(const float4*)(q + b*UD + lane*4);
  float4 w4 = *(const float4*)(wc + lane*4);
  float4 v4 = *(const float4*)(V + lane*4);
  float cv = cov[b*SD + s];
  float4 e4 = *(const float4*)(encW1 + ((long long)b*SD + s)*UD + lane*4);
  float acc = v4.x * tanhf(e4.x + q4.x + cv*w4.x)
            + v4.y * tanhf(e4.y + q4.y + cv*w4.y)
            + v4.z * tanhf(e4.z + q4.z + cv*w4.z)
            + v4.w * tanhf(e4.w + q4.w + cv*w4.w);
  for (int off = 32; off; off >>= 1) acc += __shfl_xor(acc, off);
  if (lane == 0) sc[b*SD + s] = acc;
}

// ---- masked softmax + gumbel argmax + coverage + outputs + chosen gather ----
// one block per batch
__global__ void k_soft(const float* __restrict__ sc, const int* __restrict__ nn,
                       const float* __restrict__ un, int m,
                       float* __restrict__ cov, float* __restrict__ covl,
                       float* __restrict__ out, float* __restrict__ xT){
  __shared__ float redf[4];
  __shared__ float redc[4];
  __shared__ int   redi[4];
  __shared__ float s_mx, s_sum;
  __shared__ int   s_k;
  int b = blockIdx.x; int t = threadIdx.x;
  int n = nn[b];
  // masked max
  float lmax = -3.4e38f;
  for (int s = t; s < SD; s += 256){
    float v = sc[b*SD + s];
    if (s <= n) lmax = fmaxf(lmax, v);
  }
  for (int off = 32; off; off >>= 1) lmax = fmaxf(lmax, __shfl_xor(lmax, off));
  if ((t & 63) == 0) redf[t >> 6] = lmax;
  __syncthreads();
  if (t == 0) s_mx = fmaxf(fmaxf(redf[0], redf[1]), fmaxf(redf[2], redf[3]));
  __syncthreads();
  float mx = s_mx;
  // exp + sum
  float ev[2] = {0.f, 0.f};
  float lsum = 0.f;
  #pragma unroll
  for (int sl = 0; sl < 2; ++sl){
    int s = t + sl*256;
    if (s < SD && s <= n){
      ev[sl] = expf(sc[b*SD + s] - mx);
      lsum += ev[sl];
    }
  }
  for (int off = 32; off; off >>= 1) lsum += __shfl_xor(lsum, off);
  if ((t & 63) == 0) redf[t >> 6] = lsum;
  __syncthreads();
  if (t == 0) s_sum = redf[0] + redf[1] + redf[2] + redf[3];
  __syncthreads();
  float den = s_sum;
  // aj, gumbel argmax, coverage
  float bestv = -3.4e38f; int besti = SD;
  float lcl = 0.f;
  #pragma unroll
  for (int sl = 0; sl < 2; ++sl){
    int s = t + sl*256;
    if (s < SD){
      float aj = ev[sl] / den;                 // masked -> 0
      float u = un[((long long)m*NB + b)*SD + s];
      float g = -logf(-logf(u + 1e-10f) + 1e-10f);
      float yl = logf(aj + 1e-12f) + g;
      float cv = cov[b*SD + s];
      lcl += fminf(aj, cv);
      cov[b*SD + s] = cv + aj;
      out[OFF_ATT + ((long long)b*SD + s)*MS + m] = aj;
      if (yl > bestv){ bestv = yl; besti = s; }
    }
  }
  for (int off = 32; off; off >>= 1){
    float ov = __shfl_xor(bestv, off); int oi = __shfl_xor(besti, off);
    if (ov > bestv || (ov == bestv && oi < besti)){ bestv = ov; besti = oi; }
  }
  for (int off = 32; off; off >>= 1) lcl += __shfl_xor(lcl, off);
  if ((t & 63) == 0){ redf[t >> 6] = bestv; redi[t >> 6] = besti; redc[t >> 6] = lcl; }
  __syncthreads();
  if (t == 0){
    float bv = redf[0]; int bi = redi[0];
    for (int w = 1; w < 4; ++w)
      if (redf[w] > bv || (redf[w] == bv && redi[w] < bi)){ bv = redf[w]; bi = redi[w]; }
    s_k = bi;
    covl[b] += redc[0] + redc[1] + redc[2] + redc[3];
  }
  __syncthreads();
  int k = s_k;
  #pragma unroll
  for (int sl = 0; sl < 2; ++sl){
    int s = t + sl*256;
    if (s < SD) out[OFF_PTR + ((long long)b*SD + s)*MS + m] = (s == k) ? 1.0f : 0.0f;
  }
  // chosen = encoder_out[b, k, :] -> next x (transposed)
  const float* er = out + OFF_ENC + ((long long)b*SD + k)*ED;
  for (int e = t; e < ED; e += 256) xT[e*NB + b] = er[e];
}

__global__ void k_fin(const float* __restrict__ covl, float* __restrict__ out){
  if (threadIdx.x == 0 && blockIdx.x == 0){
    float s = 0.f;
    for (int i = 0; i < NB; ++i) s += covl[i];
    out[OFF_COVL] = s / (float)NB;
  }
}

extern "C" void kernel_launch(void* const* d_in, const int* in_sizes, int n_in,
                              void* d_out, int out_size, void* d_ws, size_t ws_size,
                              hipStream_t stream){
  const float* h_padded    = (const float*)d_in[0];
  const float* hg          = (const float*)d_in[1];
  const int*   num_nodes   = (const int*)  d_in[2];
  const float* u_noise     = (const float*)d_in[3];
  const float* emb_special = (const float*)d_in[4];
  const float* emb_pos     = (const float*)d_in[5];
  const float* Wp          = (const float*)d_in[6];
  const float* bp          = (const float*)d_in[7];
  const float* W_ih0       = (const float*)d_in[8];
  const float* W_hh0       = (const float*)d_in[9];
  const float* b_ih0       = (const float*)d_in[10];
  const float* b_hh0       = (const float*)d_in[11];
  const float* W_ih1       = (const float*)d_in[12];
  const float* W_hh1       = (const float*)d_in[13];
  const float* b_ih1       = (const float*)d_in[14];
  const float* b_hh1       = (const float*)d_in[15];
  const float* W1          = (const float*)d_in[16];
  const float* W2          = (const float*)d_in[17];
  const float* wc          = (const float*)d_in[18];
  const float* V           = (const float*)d_in[19];
  const float* Wf          = (const float*)d_in[20];
  const float* bf          = (const float*)d_in[21];
  float* out = (float*)d_out;

  float* ws    = (float*)d_ws;
  float* encW1 = ws;  ws += (long long)NB*SD*UD;  // 2,105,344
  float* xT    = ws;  ws += IL0*NB;               // 17,504
  float* h0T   = ws;  ws += 2*HD*NB;              // 32,768
  float* h1T   = ws;  ws += 2*HD*NB;              // 32,768
  float* q     = ws;  ws += NB*UD;                // 8,192
  float* sc    = ws;  ws += NB*SD;                // 8,224
  float* cov   = ws;  ws += NB*SD;                // 8,224
  float* covl  = ws;  ws += NB;                   // 32
  float* hgT   = ws;  ws += ED*NB;                // 16,384
  float* W1T   = ws;  ws += (long long)UD*ED;     // 131,072

  k_enc  <<<NB*SD, 128, 0, stream>>>(h_padded, emb_special, num_nodes, out);
  k_misc <<<128, 256, 0, stream>>>(hg, emb_special, emb_pos, W1, xT, hgT, cov, covl, W1T);
  k_encw1<<<264, 256, 0, stream>>>(out, W1T, encW1);
  k_hid0 <<<128, 256, 0, stream>>>(hgT, Wp, bp, h0T, h1T);

  for (int m = 0; m < MS; ++m){
    float* h0c = h0T + (m & 1)*HD*NB;
    float* h0n = h0T + ((m + 1) & 1)*HD*NB;
    float* h1c = h1T + (m & 1)*HD*NB;
    float* h1n = h1T + ((m + 1) & 1)*HD*NB;
    k_gru<IL0><<<256, 192, 0, stream>>>(xT,  h0c, W_ih0, W_hh0, b_ih0, b_hh0, h0n);
    k_gru<HD> <<<256, 192, 0, stream>>>(h0n, h1c, W_ih1, W_hh1, b_ih1, b_hh1, h1n);
    k_qk     <<<36, 256, 0, stream>>>(h1n, W2, Wf, bf, emb_pos, m, q, xT, out);
    k_scores <<<2056, 256, 0, stream>>>(encW1, q, wc, V, cov, sc);
    k_soft   <<<32, 256, 0, stream>>>(sc, num_nodes, u_noise, m, cov, covl, out, xT);
  }
  k_fin<<<1, 64, 0, stream>>>(covl, out);
}

// Round 2
// 2309.791 us; speedup vs baseline: 2.6004x; 2.6004x over previous
//
#include <hip/hip_runtime.h>

constexpr int NB  = 32;     // batch
constexpr int NMX = 256;    // NMAX
constexpr int ED  = 512;    // E
constexpr int HD  = 512;    // H
constexpr int UD  = 256;    // U
constexpr int MS  = 32;     // M steps
constexpr int PD  = 4;      // P
constexpr int SD  = 257;    // S = NMAX+1
constexpr int IL0 = 547;    // E + (M-1) + P
constexpr int NI4_0 = 137;  // ceil(548/4) f4-blocks for layer0 input
constexpr int NI4_1 = 128;  // layer1 input f4-blocks
constexpr int NH4   = 128;  // hidden f4-blocks

constexpr long long OFF_PTR  = 0;
constexpr long long OFF_COVL = (long long)NB*SD*MS;              // 263168
constexpr long long OFF_ENC  = OFF_COVL + 1;                     // 263169
constexpr long long OFF_ADJ  = OFF_ENC + (long long)NB*SD*ED;    // 4473857
constexpr long long OFF_ATT  = OFF_ADJ + (long long)NB*(MS-1)*MS;// 4505601

__device__ __forceinline__ float sigf(float x){ return 1.0f/(1.0f + __expf(-x)); }
__device__ __forceinline__ float ftanh(float x){ float e = __expf(2.0f*x); return 1.0f - 2.0f/(e + 1.0f); }

// ---- encoder_out -> d_out[OFF_ENC]  (one block per (b,s) row) ----
__global__ void k_enc(const float* __restrict__ hp, const float* __restrict__ embsp,
                      const int* __restrict__ nn, float* __restrict__ out){
  int r = blockIdx.x; int b = r / SD, s = r % SD;
  float* dst = out + OFF_ENC + (long long)r*ED;
  int t = threadIdx.x;              // 128 threads, 4 floats each = 512
  if (s == 0){
    const float* src = embsp + ED;  // emb_special[1]
    int e = t*4; float4 v = *(const float4*)(src + e);
    dst[e] = v.x; dst[e+1] = v.y; dst[e+2] = v.z; dst[e+3] = v.w;
  } else if (s-1 < nn[b]){
    const float* src = hp + ((long long)b*NMX + (s-1))*ED;
    int e = t*4; float4 v = *(const float4*)(src + e);
    dst[e] = v.x; dst[e+1] = v.y; dst[e+2] = v.z; dst[e+3] = v.w;
  } else {
    int e = t*4;
    dst[e] = 0.f; dst[e+1] = 0.f; dst[e+2] = 0.f; dst[e+3] = 0.f;
  }
}

// ---- init: x4 (step-0 input, blocked), hg4, cov=0, covl=0, W1T, Wih0 repack ----
__global__ void k_misc(const float* __restrict__ hg, const float* __restrict__ embsp,
                       const float* __restrict__ embpos, const float* __restrict__ W1,
                       const float* __restrict__ Wih0, float* __restrict__ x4,
                       float* __restrict__ hg4, float* __restrict__ cov,
                       float* __restrict__ covl, float* __restrict__ W1T,
                       float* __restrict__ Wih0_4){
  int idx = blockIdx.x*blockDim.x + threadIdx.x;
  const int N0 = 548*NB;             // 17536 x4 (blocked floats)
  const int N1 = N0 + ED*NB;         // +16384 hg4
  const int N2 = N1 + NB*SD;         // +8224 cov
  const int N3 = N2 + NB;            // +32 covl
  const int N4 = N3 + UD*ED;         // +131072 W1T
  const int N5 = N4 + 1536*548;      // +841728 Wih0 repack
  for (int i = idx; i < N5; i += gridDim.x*blockDim.x){
    if (i < N0){
      int kb = i >> 7, b = (i >> 2) & 31, r = i & 3; (void)b;
      int k = kb*4 + r;
      float v;
      if (k < ED) v = embsp[k];                       // emb_special[0]
      else if (k < ED + MS - 1) v = 0.f;              // theta0 = 0
      else if (k < IL0) v = embpos[k - (ED + MS - 1)];// emb_pos[0][p]
      else v = 0.f;                                   // pad
      x4[i] = v;
    } else if (i < N1){
      int j = i - N0;
      int kb = j >> 7, b = (j >> 2) & 31, r = j & 3;
      int k = kb*4 + r;
      hg4[j] = hg[(long long)b*ED + k];
    } else if (i < N2){
      cov[i - N1] = 0.f;
    } else if (i < N3){
      covl[i - N2] = 0.f;
    } else if (i < N4){
      int j = i - N3; int k = j / UD, u = j % UD;
      W1T[j] = W1[(long long)u*ED + k];
    } else {
      int j = i - N4; int row = j / 548, c = j % 548;
      Wih0_4[j] = (c < IL0) ? Wih0[(long long)row*IL0 + c] : 0.f;
    }
  }
}

// ---- enc_W1 = encoder_out @ W1.T  as tiled GEMM: A[8224x512] x B[512x256] ----
__global__ __launch_bounds__(256) void k_encw1(const float* __restrict__ out,
                        const float4* __restrict__ W1T4, float4* __restrict__ encW1){
  __shared__ __align__(16) float As[16][68];
  __shared__ __align__(16) float Bs[16][68];
  int t = threadIdx.x;
  int bm = blockIdx.x >> 2, bn = blockIdx.x & 3;
  int m0 = bm*64, n0 = bn*64;
  const float* A = out + OFF_ENC;
  int tm = t >> 4, tn = t & 15;
  float4 acc[4];
  #pragma unroll
  for (int i = 0; i < 4; ++i) acc[i] = {0.f,0.f,0.f,0.f};
  int arow = t >> 2, akq = t & 3;
  int bk = t >> 4, bnq = t & 15;
  for (int k0 = 0; k0 < 512; k0 += 16){
    float av[4];
    bool okA = (m0 + arow) < NB*SD;
    long long abase = (long long)(m0 + arow)*ED + k0 + akq*4;
    #pragma unroll
    for (int j = 0; j < 4; ++j) av[j] = okA ? A[abase + j] : 0.f;
    float4 bv = W1T4[(long long)(k0 + bk)*64 + (n0 >> 2) + bnq];
    __syncthreads();
    #pragma unroll
    for (int j = 0; j < 4; ++j) As[akq*4 + j][arow] = av[j];
    *(float4*)&Bs[bk][bnq*4] = bv;
    __syncthreads();
    #pragma unroll
    for (int kk = 0; kk < 16; ++kk){
      float4 a = *(const float4*)&As[kk][tm*4];
      float4 bq = *(const float4*)&Bs[kk][tn*4];
      acc[0].x += a.x*bq.x; acc[0].y += a.x*bq.y; acc[0].z += a.x*bq.z; acc[0].w += a.x*bq.w;
      acc[1].x += a.y*bq.x; acc[1].y += a.y*bq.y; acc[1].z += a.y*bq.z; acc[1].w += a.y*bq.w;
      acc[2].x += a.z*bq.x; acc[2].y += a.z*bq.y; acc[2].z += a.z*bq.z; acc[2].w += a.z*bq.w;
      acc[3].x += a.w*bq.x; acc[3].y += a.w*bq.y; acc[3].z += a.w*bq.z; acc[3].w += a.w*bq.w;
    }
  }
  #pragma unroll
  for (int i = 0; i < 4; ++i){
    int r = m0 + tm*4 + i;
    if (r < NB*SD) encW1[(long long)r*64 + (n0 >> 2) + tn] = acc[i];
  }
}

// ---- dec_hidden init: tanh(hg @ Wp.T + bp) -> h0/h1 (blocked) ----
__global__ void k_hid0(const float4* __restrict__ hg4, const float4* __restrict__ Wp4,
                       const float* __restrict__ bp, float* __restrict__ h0,
                       float* __restrict__ h1){
  int t = threadIdx.x; int b = t & 31;
  int row = blockIdx.x*8 + (t >> 5);               // 0..1023
  const float4* w = Wp4 + (long long)row*128;
  float acc = bp[row];
  #pragma unroll 4
  for (int i = 0; i < 128; ++i){
    float4 wv = w[i], xv = hg4[i*NB + b];
    acc += wv.x*xv.x + wv.y*xv.y + wv.z*xv.z + wv.w*xv.w;
  }
  float v = ftanh(acc);
  int h = row & 511;
  int idx = (h >> 2)*128 + b*4 + (h & 3);
  if (row < HD) h0[idx] = v;
  else          h1[idx] = v;
}

// ---- one GRU layer step, 3 gates fused, k-split 8 ----
// block = 512 = 2 h  x 32 b x 8 ks ; grid = 256
template<int NI4>
__global__ __launch_bounds__(512) void k_gru(const float4* __restrict__ x4,
                      const float4* __restrict__ h4,
                      const float4* __restrict__ Wih4, const float4* __restrict__ Whh4,
                      const float* __restrict__ bih, const float* __restrict__ bhh,
                      float* __restrict__ outT){
  __shared__ float part[2][NB][8][6];
  int t = threadIdx.x;
  int b = t & 31, ks = (t >> 5) & 7, hl = (t >> 8) & 1;
  int h = blockIdx.x*2 + hl;
  float ai0 = 0.f, ai1 = 0.f, ai2 = 0.f, ah0 = 0.f, ah1 = 0.f, ah2 = 0.f;
  {
    const float4* w0 = Wih4 + (long long)(0*HD + h)*NI4;
    const float4* w1 = Wih4 + (long long)(1*HD + h)*NI4;
    const float4* w2 = Wih4 + (long long)(2*HD + h)*NI4;
    int s0 = (ks*NI4) >> 3, e0 = ((ks + 1)*NI4) >> 3;
    for (int kb = s0; kb < e0; ++kb){
      float4 xv = x4[kb*NB + b];
      float4 a = w0[kb], c = w1[kb], d = w2[kb];
      ai0 += xv.x*a.x + xv.y*a.y + xv.z*a.z + xv.w*a.w;
      ai1 += xv.x*c.x + xv.y*c.y + xv.z*c.z + xv.w*c.w;
      ai2 += xv.x*d.x + xv.y*d.y + xv.z*d.z + xv.w*d.w;
    }
  }
  {
    const float4* w0 = Whh4 + (long long)(0*HD + h)*NH4;
    const float4* w1 = Whh4 + (long long)(1*HD + h)*NH4;
    const float4* w2 = Whh4 + (long long)(2*HD + h)*NH4;
    int s1 = ks*16, e1 = s1 + 16;
    for (int kb = s1; kb < e1; ++kb){
      float4 xv = h4[kb*NB + b];
      float4 a = w0[kb], c = w1[kb], d = w2[kb];
      ah0 += xv.x*a.x + xv.y*a.y + xv.z*a.z + xv.w*a.w;
      ah1 += xv.x*c.x + xv.y*c.y + xv.z*c.z + xv.w*c.w;
      ah2 += xv.x*d.x + xv.y*d.y + xv.z*d.z + xv.w*d.w;
    }
  }
  part[hl][b][ks][0] = ai0; part[hl][b][ks][1] = ai1; part[hl][b][ks][2] = ai2;
  part[hl][b][ks][3] = ah0; part[hl][b][ks][4] = ah1; part[hl][b][ks][5] = ah2;
  __syncthreads();
  if (t < 64){
    int b2 = t & 31, hl2 = t >> 5;
    int h2 = blockIdx.x*2 + hl2;
    float g0=0.f,g1=0.f,g2=0.f,g3=0.f,g4=0.f,g5=0.f;
    #pragma unroll
    for (int k = 0; k < 8; ++k){
      g0 += part[hl2][b2][k][0]; g1 += part[hl2][b2][k][1]; g2 += part[hl2][b2][k][2];
      g3 += part[hl2][b2][k][3]; g4 += part[hl2][b2][k][4]; g5 += part[hl2][b2][k][5];
    }
    float gir = g0 + bih[h2], giz = g1 + bih[HD + h2], gin = g2 + bih[2*HD + h2];
    float ghr = g3 + bhh[h2], ghz = g4 + bhh[HD + h2], ghn = g5 + bhh[2*HD + h2];
    float r = sigf(gir + ghr);
    float z = sigf(giz + ghz);
    float nn = ftanh(gin + r*ghn);
    int idx = (h2 >> 2)*128 + b2*4 + (h2 & 3);
    float hp = ((const float*)h4)[idx];
    outT[idx] = (1.f - z)*nn + z*hp;
  }
}

// ---- fused attention: q/theta -> scores -> softmax/gumbel/cov/outputs/gather ----
// one block (512 thr) per batch b
__global__ __launch_bounds__(512) void k_attn(const float4* __restrict__ h1,
                      const float* __restrict__ W2, const float* __restrict__ Wf,
                      const float* __restrict__ bfv, const float* __restrict__ embpos,
                      const float4* __restrict__ encW1, const float* __restrict__ wc,
                      const float* __restrict__ V, const int* __restrict__ nn,
                      const float* __restrict__ un, int m,
                      float* __restrict__ cov, float* __restrict__ covl,
                      float* __restrict__ out, float4* __restrict__ x4){
  __shared__ float4 h1s4[128];
  __shared__ float4 q4s[64];
  __shared__ float4 wc4[64];
  __shared__ float4 V4s[64];
  __shared__ float scs[257];
  __shared__ float red[8]; __shared__ int redi[8]; __shared__ float redc[8];
  __shared__ float s_mx, s_den; __shared__ int s_k;
  int t = threadIdx.x, b = blockIdx.x;
  // stage 0: stage h1[b], wc, V into LDS
  if (t < 128) h1s4[t] = h1[t*NB + b];
  else if (t < 192) wc4[t - 128] = ((const float4*)wc)[t - 128];
  else if (t < 256) V4s[t - 192] = ((const float4*)V)[t - 192];
  __syncthreads();
  // stage 1: q = h1 @ W2.T (into LDS), theta -> adj + x4, pos-emb for next step
  if (t < 256){
    const float4* w = (const float4*)W2 + (long long)t*128;
    float acc = 0.f;
    #pragma unroll 4
    for (int i = 0; i < 128; ++i){
      float4 wv = w[i], hv = h1s4[i];
      acc += wv.x*hv.x + wv.y*hv.y + wv.z*hv.z + wv.w*hv.w;
    }
    ((float*)q4s)[t] = acc;
  } else if (t < 287){
    int j = t - 256;
    const float4* w = (const float4*)Wf + (long long)j*128;
    float acc = 0.f;
    #pragma unroll 4
    for (int i = 0; i < 128; ++i){
      float4 wv = w[i], hv = h1s4[i];
      acc += wv.x*hv.x + wv.y*hv.y + wv.z*hv.z + wv.w*hv.w;
    }
    float th = (m < 1) ? 0.f : sigf(acc + bfv[j]);
    out[OFF_ADJ + (long long)b*(MS-1)*MS + (long long)j*MS + m] = th;
    int k = ED + j;
    ((float*)x4)[(k >> 2)*128 + b*4 + (k & 3)] = th;
  } else if (t == 287 && m + 1 < MS){
    #pragma unroll
    for (int p = 0; p < PD; ++p){
      int k = ED + MS - 1 + p;
      ((float*)x4)[(k >> 2)*128 + b*4 + (k & 3)] = embpos[(m+1)*PD + p];
    }
  }
  __syncthreads();
  // stage 2: scores
  float cv = 0.f;
  if (t < 257){
    cv = cov[b*SD + t];
    const float4* e4 = encW1 + ((long long)b*SD + t)*64;
    float acc = 0.f;
    #pragma unroll 2
    for (int i = 0; i < 64; ++i){
      float4 e = e4[i], q = q4s[i], w = wc4[i], v = V4s[i];
      acc += v.x*ftanh(e.x + q.x + cv*w.x);
      acc += v.y*ftanh(e.y + q.y + cv*w.y);
      acc += v.z*ftanh(e.z + q.z + cv*w.z);
      acc += v.w*ftanh(e.w + q.w + cv*w.w);
    }
    scs[t] = acc;
  }
  __syncthreads();
  // stage 3: masked softmax + gumbel argmax + coverage
  int n = nn[b];
  float v1 = (t < 257 && t <= n) ? scs[t] : -3.4e38f;
  for (int off = 32; off; off >>= 1) v1 = fmaxf(v1, __shfl_xor(v1, off));
  if ((t & 63) == 0) red[t >> 6] = v1;
  __syncthreads();
  if (t == 0){ float mm = red[0]; for (int w = 1; w < 8; ++w) mm = fmaxf(mm, red[w]); s_mx = mm; }
  __syncthreads();
  float ev = (t < 257 && t <= n) ? __expf(scs[t] - s_mx) : 0.f;
  float v2 = ev;
  for (int off = 32; off; off >>= 1) v2 += __shfl_xor(v2, off);
  if ((t & 63) == 0) red[t >> 6] = v2;
  __syncthreads();
  if (t == 0){ float ss = 0.f; for (int w = 0; w < 8; ++w) ss += red[w]; s_den = ss; }
  __syncthreads();
  float aj = (t < 257) ? ev / s_den : 0.f;
  float yl = -3.4e38f; int idx = SD;
  float lcl = 0.f;
  if (t < 257){
    float u = un[((long long)m*NB + b)*SD + t];
    float g = -__logf(-__logf(u + 1e-10f) + 1e-10f);
    yl = __logf(aj + 1e-12f) + g;
    idx = t;
    lcl = fminf(aj, cv);
    cov[b*SD + t] = cv + aj;
    out[OFF_ATT + ((long long)b*SD + t)*MS + m] = aj;
  }
  for (int off = 32; off; off >>= 1){
    float oy = __shfl_xor(yl, off); int oi = __shfl_xor(idx, off);
    if (oy > yl || (oy == yl && oi < idx)){ yl = oy; idx = oi; }
  }
  for (int off = 32; off; off >>= 1) lcl += __shfl_xor(lcl, off);
  if ((t & 63) == 0){ red[t >> 6] = yl; redi[t >> 6] = idx; redc[t >> 6] = lcl; }
  __syncthreads();
  if (t == 0){
    float by = red[0]; int bi = redi[0]; float cl = redc[0];
    for (int w = 1; w < 8; ++w){
      if (red[w] > by || (red[w] == by && redi[w] < bi)){ by = red[w]; bi = redi[w]; }
      cl += redc[w];
    }
    s_k = bi;
    covl[b] += cl;
  }
  __syncthreads();
  int kk = s_k;
  if (t < 257) out[OFF_PTR + ((long long)b*SD + t)*MS + m] = (t == kk) ? 1.f : 0.f;
  // chosen = encoder_out[b, kk, :] -> next x (blocked)
  const float* er = out + OFF_ENC + ((long long)b*SD + kk)*ED;
  if (t < 128){
    float4 v; v.x = er[t*4]; v.y = er[t*4+1]; v.z = er[t*4+2]; v.w = er[t*4+3];
    x4[t*NB + b] = v;
  }
}

__global__ void k_fin(const float* __restrict__ covl, float* __restrict__ out){
  if (threadIdx.x == 0 && blockIdx.x == 0){
    float s = 0.f;
    for (int i = 0; i < NB; ++i) s += covl[i];
    out[OFF_COVL] = s / (float)NB;
  }
}

extern "C" void kernel_launch(void* const* d_in, const int* in_sizes, int n_in,
                              void* d_out, int out_size, void* d_ws, size_t ws_size,
                              hipStream_t stream){
  const float* h_padded    = (const float*)d_in[0];
  const float* hg          = (const float*)d_in[1];
  const int*   num_nodes   = (const int*)  d_in[2];
  const float* u_noise     = (const float*)d_in[3];
  const float* emb_special = (const float*)d_in[4];
  const float* emb_pos     = (const float*)d_in[5];
  const float* Wp          = (const float*)d_in[6];
  const float* bp          = (const float*)d_in[7];
  const float* W_ih0       = (const float*)d_in[8];
  const float* W_hh0       = (const float*)d_in[9];
  const float* b_ih0       = (const float*)d_in[10];
  const float* b_hh0       = (const float*)d_in[11];
  const float* W_ih1       = (const float*)d_in[12];
  const float* W_hh1       = (const float*)d_in[13];
  const float* b_ih1       = (const float*)d_in[14];
  const float* b_hh1       = (const float*)d_in[15];
  const float* W1          = (const float*)d_in[16];
  const float* W2          = (const float*)d_in[17];
  const float* wc          = (const float*)d_in[18];
  const float* V           = (const float*)d_in[19];
  const float* Wf          = (const float*)d_in[20];
  const float* bf          = (const float*)d_in[21];
  float* out = (float*)d_out;

  float* ws      = (float*)d_ws;
  float* encW1   = ws;  ws += (long long)NB*SD*UD;   // 2,105,344
  float* Wih0_4  = ws;  ws += (long long)1536*548;   // 841,728
  float* W1T     = ws;  ws += (long long)UD*ED;      // 131,072
  float* x4      = ws;  ws += 548*NB;                // 17,536
  float* hg4     = ws;  ws += ED*NB;                 // 16,384
  float* h0      = ws;  ws += 2*HD*NB;               // 32,768
  float* h1      = ws;  ws += 2*HD*NB;               // 32,768
  float* cov     = ws;  ws += NB*SD;                 // 8,224
  float* covl    = ws;  ws += NB;                    // 32

  k_enc  <<<NB*SD, 128, 0, stream>>>(h_padded, emb_special, num_nodes, out);
  k_misc <<<256, 256, 0, stream>>>(hg, emb_special, emb_pos, W1, W_ih0,
                                   x4, hg4, cov, covl, W1T, Wih0_4);
  k_encw1<<<516, 256, 0, stream>>>(out, (const float4*)W1T, (float4*)encW1);
  k_hid0 <<<128, 256, 0, stream>>>((const float4*)hg4, (const float4*)Wp, bp, h0, h1);

  for (int m = 0; m < MS; ++m){
    float* h0c = h0 + (m & 1)*HD*NB;
    float* h0n = h0 + ((m + 1) & 1)*HD*NB;
    float* h1c = h1 + (m & 1)*HD*NB;
    float* h1n = h1 + ((m + 1) & 1)*HD*NB;
    k_gru<NI4_0><<<256, 512, 0, stream>>>((const float4*)x4, (const float4*)h0c,
        (const float4*)Wih0_4, (const float4*)W_hh0, b_ih0, b_hh0, h0n);
    k_gru<NI4_1><<<256, 512, 0, stream>>>((const float4*)h0n, (const float4*)h1c,
        (const float4*)W_ih1, (const float4*)W_hh1, b_ih1, b_hh1, h1n);
    k_attn<<<NB, 512, 0, stream>>>((const float4*)h1n, W2, Wf, bf, emb_pos,
        (const float4*)encW1, wc, V, num_nodes, u_noise, m, cov, covl, out, (float4*)x4);
  }
  k_fin<<<1, 64, 0, stream>>>(covl, out);
}